// Round 3
// baseline (167.656 us; speedup 1.0000x reference)
//
#include <hip/hip_runtime.h>
#include <stdint.h>

#define SEQ 2048
#define NH  16

typedef __bf16 bf16x8 __attribute__((ext_vector_type(8)));
typedef float  f32x4  __attribute__((ext_vector_type(4)));

#if __has_builtin(__builtin_amdgcn_exp2f)
#define EXP2(x) __builtin_amdgcn_exp2f(x)
#else
#define EXP2(x) exp2f(x)
#endif

#define WAITV0 asm volatile("s_waitcnt vmcnt(0)" ::: "memory")
#define WAITV4 asm volatile("s_waitcnt vmcnt(4)" ::: "memory")
#define WAITV8 asm volatile("s_waitcnt vmcnt(8)" ::: "memory")
#define SBAR() do { __builtin_amdgcn_sched_barrier(0); __builtin_amdgcn_s_barrier(); __builtin_amdgcn_sched_barrier(0); } while (0)

__device__ __forceinline__ unsigned short f2bf(float f) {
  union { float f; uint32_t u; } v; v.f = f;
  uint32_t r = v.u + 0x7fffu + ((v.u >> 16) & 1u);
  return (unsigned short)(r >> 16);
}

__device__ __forceinline__ void gll16(const void* g, void* l) {
  __builtin_amdgcn_global_load_lds((const __attribute__((address_space(1))) void*)g,
                                   (__attribute__((address_space(3))) void*)l, 16, 0, 0);
}

__device__ __forceinline__ f32x4 mfma16(bf16x8 a, bf16x8 b, f32x4 c) {
  return __builtin_amdgcn_mfma_f32_16x16x32_bf16(a, b, c, 0, 0, 0);
}

// ---------------- fused fp32 -> bf16 convert (7 jobs, 1 launch) ----------------
struct CvtJobs {
  const float* s[7];
  unsigned short* d[7];
  int n4[7];
};

__global__ void cvt_all(CvtJobs J) {
  int j = blockIdx.y;
  const float* __restrict__ s = J.s[j];
  unsigned short* __restrict__ d = J.d[j];
  int n4 = J.n4[j];
  int st = gridDim.x * blockDim.x;
  for (int i = blockIdx.x * blockDim.x + threadIdx.x; i < n4; i += st) {
    float4 v = ((const float4*)s)[i];
    union { unsigned short u[4]; uint2 q; } o;
    o.u[0] = f2bf(v.x); o.u[1] = f2bf(v.y); o.u[2] = f2bf(v.z); o.u[3] = f2bf(v.w);
    ((uint2*)d)[i] = o.q;
  }
}

// ---------------- GEMM 128x128, BK=64, double-buffered, fused multi-job ----------------
// C[m][n] = (sum_k A[m][k]*W[n][k] + bias[n]) * scale
// mode 0: bf16 [B,H,S,DK]; mode 1: bf16 [B,H,DK,S]; mode 2: fp32 [M][N].
struct GemmJobs {
  const unsigned short* A[3];
  const unsigned short* W[3];
  const float* bias[3];
  void* out[3];
  float scale[3];
  int mode[3];
};

__global__ __launch_bounds__(256, 2) void gemm128(GemmJobs J) {
  __shared__ alignas(16) unsigned short Asm[2][128 * 64];  // 16KB each
  __shared__ alignas(16) unsigned short Bsm[2][128 * 64];
  const int tid = threadIdx.x;
  const int l = tid & 63, w = tid >> 6;
  const int wr = w >> 1, wc = w & 1;
  const int lg = l >> 4, lo = l & 15;

  // XCD-aware swizzle (nwg % 8 == 0)
  const int nwg = gridDim.x;
  const int id = blockIdx.x;
  const int swz = (id & 7) * (nwg >> 3) + (id >> 3);
  const int g = swz >> 8;          // 256 blocks per job
  const int rem = swz & 255;
  const int m0 = (rem & 31) * 128; // mb fastest: consecutive blocks share W panel
  const int n0 = (rem >> 5) * 128;

  const unsigned short* __restrict__ A = J.A[g];
  const unsigned short* __restrict__ W = J.W[g];
  const float* __restrict__ bias = J.bias[g];
  const int mode = J.mode[g];
  const float scale = J.scale[g];

  f32x4 acc[4][4] = {};

  // stage tile kt into buffer b: 4 A-chunks + 4 B-chunks per thread (8 gll16/wave)
#define GSTAGE(b, kt)                                                                   \
  do {                                                                                  \
    _Pragma("unroll")                                                                   \
    for (int it = 0; it < 4; ++it) {                                                    \
      int chunk = it * 256 + tid;                                                       \
      int row = chunk >> 3, c = chunk & 7;                                              \
      const char* src = (const char*)A + (((size_t)(m0 + row) << 10) + ((kt) << 6)) * 2 \
                        + ((c ^ (row & 7)) << 4);                                       \
      gll16(src, (char*)Asm[b] + ((it * 256 + (tid & ~63)) << 4));                      \
    }                                                                                   \
    _Pragma("unroll")                                                                   \
    for (int it = 0; it < 4; ++it) {                                                    \
      int chunk = it * 256 + tid;                                                       \
      int row = chunk >> 3, c = chunk & 7;                                              \
      const char* src = (const char*)W + (((size_t)(n0 + row) << 10) + ((kt) << 6)) * 2 \
                        + ((c ^ (row & 7)) << 4);                                       \
      gll16(src, (char*)Bsm[b] + ((it * 256 + (tid & ~63)) << 4));                      \
    }                                                                                   \
  } while (0)

  GSTAGE(0, 0);

  for (int kt = 0; kt < 16; ++kt) {
    const int cur = kt & 1;
    if (kt < 15) {
      GSTAGE(cur ^ 1, kt + 1);
      WAITV8;            // tile kt's 8 loads done; 8 in flight
    } else {
      WAITV0;
    }
    SBAR();
#pragma unroll
    for (int kf = 0; kf < 2; ++kf) {
      bf16x8 af[4], bfr[4];
#pragma unroll
      for (int mf = 0; mf < 4; ++mf) {
        int row = wr * 64 + mf * 16 + lo;
        int pos = (kf * 4 + lg) ^ (row & 7);
        af[mf] = *(const bf16x8*)((const char*)Asm[cur] + row * 128 + pos * 16);
      }
#pragma unroll
      for (int nf = 0; nf < 4; ++nf) {
        int row = wc * 64 + nf * 16 + lo;
        int pos = (kf * 4 + lg) ^ (row & 7);
        bfr[nf] = *(const bf16x8*)((const char*)Bsm[cur] + row * 128 + pos * 16);
      }
#pragma unroll
      for (int mf = 0; mf < 4; ++mf)
#pragma unroll
        for (int nf = 0; nf < 4; ++nf)
          acc[mf][nf] = mfma16(af[mf], bfr[nf], acc[mf][nf]);
    }
    SBAR();              // all waves done reading buf[cur] before it is restaged
  }
#undef GSTAGE

  // epilogue
#pragma unroll
  for (int mf = 0; mf < 4; ++mf)
#pragma unroll
    for (int nf = 0; nf < 4; ++nf) {
      int gcol = n0 + wc * 64 + nf * 16 + lo;
      float bv = bias[gcol];
#pragma unroll
      for (int r = 0; r < 4; ++r) {
        int grow = m0 + wr * 64 + mf * 16 + lg * 4 + r;
        float v = (acc[mf][nf][r] + bv) * scale;
        if (mode == 2) {
          ((float*)J.out[g])[((size_t)grow << 10) + gcol] = v;
        } else {
          int b = grow >> 11, s = grow & 2047, h = gcol >> 6, dk = gcol & 63;
          size_t idx;
          if (mode == 0) idx = ((((size_t)((b << 4) + h) << 11) + s) << 6) + dk;
          else           idx = ((((size_t)((b << 4) + h) << 6) + dk) << 11) + s;
          ((__bf16*)J.out[g])[idx] = (__bf16)v;
        }
      }
    }
}

// ---------------- flash attention (swapped QK^T, double-buffered K/V) ----------------
// Qb: [B*H][S][64] bf16. Kb: same, pre-scaled by 0.125*log2(e). Vt: [B*H][64][S] bf16.
// 1D grid 512 (XCD-swizzled -> bh, qtile), 256 threads (4 waves x 32 q-rows).
__global__ __launch_bounds__(256, 2) void attn_kernel(const unsigned short* __restrict__ Qb,
                                                      const unsigned short* __restrict__ Kb,
                                                      const unsigned short* __restrict__ Vt,
                                                      unsigned short* __restrict__ ctx) {
  __shared__ alignas(16) unsigned short Ksm[2][64 * 64];  // [kv][64dk] swizzled, dbuf
  __shared__ alignas(16) unsigned short Vsm[2][64 * 64];  // [dk][64kv] swizzled, dbuf
  __shared__ alignas(16) unsigned short Psm[4 * 32 * 64]; // per-wave [32q][64kv] swizzled
  const int tid = threadIdx.x;
  const int l = tid & 63, w = tid >> 6;
  const int lg = l >> 4, lo = l & 15;

  // XCD swizzle: 512 blocks, chunk 64 -> each XCD owns 4 complete heads
  const int id = blockIdx.x;
  const int swz = (id & 7) * 64 + (id >> 3);
  const int bh = swz >> 4;
  const int qt = swz & 15;

  const unsigned short* Qp = Qb + (size_t)bh * SEQ * 64;
  const unsigned short* Kp = Kb + (size_t)bh * SEQ * 64;
  const unsigned short* Vp = Vt + (size_t)bh * 64 * SEQ;
  const int q0 = qt * 128 + w * 32;

  // Q fragments: lane holds Q[q0 + qf*16 + lo][kc*32 + lg*8 ..+7]
  bf16x8 qf[2][2];
#pragma unroll
  for (int mf = 0; mf < 2; ++mf)
#pragma unroll
    for (int kc = 0; kc < 2; ++kc)
      qf[mf][kc] = *(const bf16x8*)((const char*)Qp + (((size_t)(q0 + mf * 16 + lo)) << 7) + kc * 64 + lg * 16);
  WAITV0;  // Q loads complete before prefetch pipeline starts

  f32x4 O[2][4] = {};
  float m_[2], l_[2];
  m_[0] = m_[1] = -1e30f;
  l_[0] = l_[1] = 0.f;

  // stage K/V tile t into buffer b: 2 K-chunks + 2 V-chunks per thread (4 gll16/wave)
#define ASTAGE(b, t)                                                                      \
  do {                                                                                    \
    const int kv0s = (t) << 6;                                                            \
    _Pragma("unroll")                                                                     \
    for (int it = 0; it < 2; ++it) {                                                      \
      int chunk = it * 256 + tid;                                                         \
      int row = chunk >> 3, c = chunk & 7;                                                \
      const char* ksrc = (const char*)Kp + ((size_t)(kv0s + row) << 7) + ((c ^ (row & 7)) << 4); \
      gll16(ksrc, (char*)Ksm[b] + ((it * 256 + (tid & ~63)) << 4));                       \
      const char* vsrc = (const char*)Vp + ((size_t)row << 12) + (kv0s << 1) + ((c ^ (row & 7)) << 4); \
      gll16(vsrc, (char*)Vsm[b] + ((it * 256 + (tid & ~63)) << 4));                       \
    }                                                                                     \
  } while (0)

  ASTAGE(0, 0);

  for (int t = 0; t < SEQ / 64; ++t) {
    const int cur = t & 1;
    if (t < SEQ / 64 - 1) {
      ASTAGE(cur ^ 1, t + 1);
      WAITV4;
    } else {
      WAITV0;
    }
    SBAR();

    // S^T = K Q^T : sfr[kvf][qf][r] = S[kv=kvf*16+lg*4+r][q=qf*16+lo]
    f32x4 sfr[4][2] = {};
#pragma unroll
    for (int kc = 0; kc < 2; ++kc) {
      bf16x8 kfr[4];
#pragma unroll
      for (int kvf = 0; kvf < 4; ++kvf) {
        int kv = kvf * 16 + lo;
        int pos = (kc * 4 + lg) ^ (kv & 7);
        kfr[kvf] = *(const bf16x8*)((const char*)Ksm[cur] + kv * 128 + pos * 16);
      }
#pragma unroll
      for (int kvf = 0; kvf < 4; ++kvf)
#pragma unroll
        for (int qfi = 0; qfi < 2; ++qfi)
          sfr[kvf][qfi] = mfma16(kfr[kvf], qf[qfi][kc], sfr[kvf][qfi]);
    }

    // online softmax: each lane owns q = qf*16+lo, 16 S-values (kv = kvf*16+lg*4+r)
    float tmx[2];
#pragma unroll
    for (int qfi = 0; qfi < 2; ++qfi) {
      float a0 = fmaxf(fmaxf(sfr[0][qfi][0], sfr[0][qfi][1]), fmaxf(sfr[0][qfi][2], sfr[0][qfi][3]));
      float a1 = fmaxf(fmaxf(sfr[1][qfi][0], sfr[1][qfi][1]), fmaxf(sfr[1][qfi][2], sfr[1][qfi][3]));
      float a2 = fmaxf(fmaxf(sfr[2][qfi][0], sfr[2][qfi][1]), fmaxf(sfr[2][qfi][2], sfr[2][qfi][3]));
      float a3 = fmaxf(fmaxf(sfr[3][qfi][0], sfr[3][qfi][1]), fmaxf(sfr[3][qfi][2], sfr[3][qfi][3]));
      float mx = fmaxf(fmaxf(a0, a1), fmaxf(a2, a3));
      mx = fmaxf(mx, __shfl_xor(mx, 16));
      mx = fmaxf(mx, __shfl_xor(mx, 32));
      tmx[qfi] = mx;
    }
    bool need = (tmx[0] > m_[0]) | (tmx[1] > m_[1]);
    if (__any((int)need)) {
      float facv[2];
#pragma unroll
      for (int qfi = 0; qfi < 2; ++qfi) {
        float mnew = fmaxf(m_[qfi], tmx[qfi]);
        facv[qfi] = EXP2(m_[qfi] - mnew);
        m_[qfi] = mnew;
        float ps = 0.f;
#pragma unroll
        for (int kvf = 0; kvf < 4; ++kvf)
#pragma unroll
          for (int r = 0; r < 4; ++r) {
            float p = EXP2(sfr[kvf][qfi][r] - mnew);
            sfr[kvf][qfi][r] = p;
            ps += p;
          }
        ps += __shfl_xor(ps, 16);
        ps += __shfl_xor(ps, 32);
        l_[qfi] = l_[qfi] * facv[qfi] + ps;
      }
#pragma unroll
      for (int mf = 0; mf < 2; ++mf)
#pragma unroll
        for (int r = 0; r < 4; ++r) {
          float fb = __shfl(facv[mf], lg * 4 + r);
#pragma unroll
          for (int dkf = 0; dkf < 4; ++dkf) O[mf][dkf][r] *= fb;
        }
    } else {
#pragma unroll
      for (int qfi = 0; qfi < 2; ++qfi) {
        float ps = 0.f;
#pragma unroll
        for (int kvf = 0; kvf < 4; ++kvf)
#pragma unroll
          for (int r = 0; r < 4; ++r) {
            float p = EXP2(sfr[kvf][qfi][r] - m_[qfi]);
            sfr[kvf][qfi][r] = p;
            ps += p;
          }
        ps += __shfl_xor(ps, 16);
        ps += __shfl_xor(ps, 32);
        l_[qfi] += ps;
      }
    }

    // pack P -> per-wave swizzled LDS [q 32][kv 64]
#pragma unroll
    for (int qfi = 0; qfi < 2; ++qfi) {
      int ql = qfi * 16 + lo;
      int sw = ql & 7;
#pragma unroll
      for (int kvf = 0; kvf < 4; ++kvf) {
        union { __bf16 b[4]; unsigned long long u; } pk;
#pragma unroll
        for (int r = 0; r < 4; ++r) pk.b[r] = (__bf16)sfr[kvf][qfi][r];
        int g = kvf * 2 + (lg >> 1);
        *(unsigned long long*)((char*)Psm + w * 4096 + ql * 128 + ((g ^ sw) << 4) + ((lg & 1) << 3)) = pk.u;
      }
    }

    // O += P V : A-frags from Psm, B-frags from Vsm
    bf16x8 af[2][2];
#pragma unroll
    for (int mf = 0; mf < 2; ++mf)
#pragma unroll
      for (int kc = 0; kc < 2; ++kc) {
        int ql = mf * 16 + lo;
        int pos = (kc * 4 + lg) ^ (ql & 7);
        af[mf][kc] = *(const bf16x8*)((const char*)Psm + w * 4096 + ql * 128 + pos * 16);
      }
#pragma unroll
    for (int dkf = 0; dkf < 4; ++dkf) {
      bf16x8 bvf[2];
#pragma unroll
      for (int kc = 0; kc < 2; ++kc) {
        int dk = dkf * 16 + lo;
        int pos = (kc * 4 + lg) ^ (dk & 7);
        bvf[kc] = *(const bf16x8*)((const char*)Vsm[cur] + dk * 128 + pos * 16);
      }
#pragma unroll
      for (int mf = 0; mf < 2; ++mf) {
        O[mf][dkf] = mfma16(af[mf][0], bvf[0], O[mf][dkf]);
        O[mf][dkf] = mfma16(af[mf][1], bvf[1], O[mf][dkf]);
      }
    }
    SBAR();  // all waves done reading buf[cur] before it is restaged
  }
#undef ASTAGE

  // epilogue: normalize and store ctx [B*S][1024]
  const int b = bh >> 4, h = bh & 15;
#pragma unroll
  for (int mf = 0; mf < 2; ++mf)
#pragma unroll
    for (int r = 0; r < 4; ++r) {
      float lr = __shfl(l_[mf], lg * 4 + r);
      float inv = 1.f / lr;
      int srow = q0 + mf * 16 + lg * 4 + r;
      size_t rowoff = ((size_t)(b * SEQ + srow) << 10) + h * 64;
#pragma unroll
      for (int dkf = 0; dkf < 4; ++dkf)
        ((__bf16*)ctx)[rowoff + dkf * 16 + lo] = (__bf16)(O[mf][dkf][r] * inv);
    }
}

// ---------------- launch ----------------
extern "C" void kernel_launch(void* const* d_in, const int* in_sizes, int n_in,
                              void* d_out, int out_size, void* d_ws, size_t ws_size,
                              hipStream_t stream) {
  const float* query = (const float*)d_in[0];
  const float* key_  = (const float*)d_in[1];
  const float* value = (const float*)d_in[2];
  const float* wq = (const float*)d_in[4];
  const float* bq = (const float*)d_in[5];
  const float* wk = (const float*)d_in[6];
  const float* bk = (const float*)d_in[7];
  const float* wv = (const float*)d_in[8];
  const float* bv = (const float*)d_in[9];
  const float* wo = (const float*)d_in[10];
  const float* bo = (const float*)d_in[11];

  char* ws = (char*)d_ws;
  unsigned short* xq  = (unsigned short*)(ws + 0);
  unsigned short* xk  = (unsigned short*)(ws + 8388608);
  unsigned short* xv  = (unsigned short*)(ws + 16777216);
  unsigned short* wqb = (unsigned short*)(ws + 25165824);
  unsigned short* wkb = (unsigned short*)(ws + 27262976);
  unsigned short* wvb = (unsigned short*)(ws + 29360128);
  unsigned short* wob = (unsigned short*)(ws + 31457280);
  unsigned short* Qb  = (unsigned short*)(ws + 33554432);   // [B,H,S,64]
  unsigned short* Kb  = (unsigned short*)(ws + 41943040);   // [B,H,S,64] (pre-scaled, log2e folded)
  unsigned short* Vb  = (unsigned short*)(ws + 50331648);   // [B,H,64,S]
  unsigned short* ctx = (unsigned short*)(ws + 58720256);   // [B*S,1024]

  CvtJobs cj;
  cj.s[0] = query; cj.d[0] = xq;  cj.n4[0] = 1048576;
  cj.s[1] = key_;  cj.d[1] = xk;  cj.n4[1] = 1048576;
  cj.s[2] = value; cj.d[2] = xv;  cj.n4[2] = 1048576;
  cj.s[3] = wq;    cj.d[3] = wqb; cj.n4[3] = 262144;
  cj.s[4] = wk;    cj.d[4] = wkb; cj.n4[4] = 262144;
  cj.s[5] = wv;    cj.d[5] = wvb; cj.n4[5] = 262144;
  cj.s[6] = wo;    cj.d[6] = wob; cj.n4[6] = 262144;
  cvt_all<<<dim3(256, 7), 256, 0, stream>>>(cj);

  const float kscale = 0.125f * 1.44269504088896340736f;
  GemmJobs gj;
  gj.A[0] = xq; gj.W[0] = wqb; gj.bias[0] = bq; gj.out[0] = (void*)Qb; gj.scale[0] = 1.0f;   gj.mode[0] = 0;
  gj.A[1] = xk; gj.W[1] = wkb; gj.bias[1] = bk; gj.out[1] = (void*)Kb; gj.scale[1] = kscale; gj.mode[1] = 0;
  gj.A[2] = xv; gj.W[2] = wvb; gj.bias[2] = bv; gj.out[2] = (void*)Vb; gj.scale[2] = 1.0f;   gj.mode[2] = 1;
  gemm128<<<768, 256, 0, stream>>>(gj);

  attn_kernel<<<512, 256, 0, stream>>>(Qb, Kb, Vb, ctx);

  GemmJobs oj;
  oj.A[0] = ctx; oj.W[0] = wob; oj.bias[0] = bo; oj.out[0] = d_out; oj.scale[0] = 1.0f; oj.mode[0] = 2;
  oj.A[1] = oj.A[0]; oj.W[1] = oj.W[0]; oj.bias[1] = oj.bias[0]; oj.out[1] = oj.out[0]; oj.scale[1] = 1.0f; oj.mode[1] = 2;
  oj.A[2] = oj.A[0]; oj.W[2] = oj.W[0]; oj.bias[2] = oj.bias[0]; oj.out[2] = oj.out[0]; oj.scale[2] = 1.0f; oj.mode[2] = 2;
  gemm128<<<256, 256, 0, stream>>>(oj);
}

// Round 4
// 148.477 us; speedup vs baseline: 1.1292x; 1.1292x over previous
//
#include <hip/hip_runtime.h>
#include <stdint.h>

#define SEQ 2048
#define NH  16

typedef __bf16 bf16x8 __attribute__((ext_vector_type(8)));
typedef float  f32x4  __attribute__((ext_vector_type(4)));

#if __has_builtin(__builtin_amdgcn_exp2f)
#define EXP2(x) __builtin_amdgcn_exp2f(x)
#else
#define EXP2(x) exp2f(x)
#endif

#define WAITV0 asm volatile("s_waitcnt vmcnt(0)" ::: "memory")
#define WAITV2 asm volatile("s_waitcnt vmcnt(2)" ::: "memory")
#define SBAR() do { __builtin_amdgcn_sched_barrier(0); __builtin_amdgcn_s_barrier(); __builtin_amdgcn_sched_barrier(0); } while (0)

__device__ __forceinline__ unsigned short f2bf(float f) {
  union { float f; uint32_t u; } v; v.f = f;
  uint32_t r = v.u + 0x7fffu + ((v.u >> 16) & 1u);
  return (unsigned short)(r >> 16);
}

__device__ __forceinline__ void gll16(const void* g, void* l) {
  __builtin_amdgcn_global_load_lds((const __attribute__((address_space(1))) void*)g,
                                   (__attribute__((address_space(3))) void*)l, 16, 0, 0);
}

__device__ __forceinline__ f32x4 mfma16(bf16x8 a, bf16x8 b, f32x4 c) {
  return __builtin_amdgcn_mfma_f32_16x16x32_bf16(a, b, c, 0, 0, 0);
}

// ---------------- fused fp32 -> bf16 convert (7 jobs, 1 launch) ----------------
struct CvtJobs {
  const float* s[7];
  unsigned short* d[7];
  int n4[7];
};

__global__ void cvt_all(CvtJobs J) {
  int j = blockIdx.y;
  const float* __restrict__ s = J.s[j];
  unsigned short* __restrict__ d = J.d[j];
  int n4 = J.n4[j];
  int st = gridDim.x * blockDim.x;
  for (int i = blockIdx.x * blockDim.x + threadIdx.x; i < n4; i += st) {
    float4 v = ((const float4*)s)[i];
    union { unsigned short u[4]; uint2 q; } o;
    o.u[0] = f2bf(v.x); o.u[1] = f2bf(v.y); o.u[2] = f2bf(v.z); o.u[3] = f2bf(v.w);
    ((uint2*)d)[i] = o.q;
  }
}

// ---------------- GEMM BMx128, BK=64, single-buffered (m97 structure) ----------------
// C[m][n] = (sum_k A[m][k]*W[n][k] + bias[n]) * scale
// mode 0: bf16 [B,H,S,DK]; mode 1: bf16 [B,H,DK,S]; mode 2: fp32 [M][N].
struct GemmJobs {
  const unsigned short* A[3];
  const unsigned short* W[3];
  const float* bias[3];
  void* out[3];
  float scale[3];
  int mode[3];
};

// NB = blocks per job = (4096/BM) * (1024/128)
template<int BM, int NB>
__global__ __launch_bounds__(256, (BM == 128 ? 3 : 2)) void gemm_t(GemmJobs J) {
  __shared__ alignas(16) unsigned short Asm[BM * 64];
  __shared__ alignas(16) unsigned short Bsm[128 * 64];
  constexpr int MFR = BM / 32;    // acc row-frags per wave
  constexpr int MB = 4096 / BM;   // m-blocks per job
  const int tid = threadIdx.x;
  const int l = tid & 63, w = tid >> 6;
  const int wr = w >> 1, wc = w & 1;
  const int lg = l >> 4, lo = l & 15;

  // XCD-aware swizzle (nwg % 8 == 0)
  const int nwg = gridDim.x;
  const int id = blockIdx.x;
  const int swz = (id & 7) * (nwg >> 3) + (id >> 3);
  const int g = swz / NB;
  const int rem = swz % NB;
  const int m0 = (rem % MB) * BM;     // m fastest: consecutive blocks share W panel
  const int n0 = (rem / MB) * 128;

  const unsigned short* __restrict__ A = J.A[g];
  const unsigned short* __restrict__ W = J.W[g];
  const float* __restrict__ bias = J.bias[g];
  const int mode = J.mode[g];
  const float scale = J.scale[g];

  f32x4 acc[MFR][4] = {};

  for (int kt = 0; kt < 16; ++kt) {
    // stage A (BM x 64k) and B (128 x 64k), chunk-swizzled source, linear LDS dest
#pragma unroll
    for (int it = 0; it < BM / 32; ++it) {
      int chunk = it * 256 + tid;
      int row = chunk >> 3, c = chunk & 7;
      const char* src = (const char*)A + (((size_t)(m0 + row) << 10) + (kt << 6)) * 2 + ((c ^ (row & 7)) << 4);
      gll16(src, (char*)Asm + ((it * 256 + (tid & ~63)) << 4));
    }
#pragma unroll
    for (int it = 0; it < 4; ++it) {
      int chunk = it * 256 + tid;
      int row = chunk >> 3, c = chunk & 7;
      const char* src = (const char*)W + (((size_t)(n0 + row) << 10) + (kt << 6)) * 2 + ((c ^ (row & 7)) << 4);
      gll16(src, (char*)Bsm + ((it * 256 + (tid & ~63)) << 4));
    }
    WAITV0;
    SBAR();
#pragma unroll
    for (int kf = 0; kf < 2; ++kf) {
      bf16x8 af[MFR], bfr[4];
#pragma unroll
      for (int mf = 0; mf < MFR; ++mf) {
        int row = wr * (BM / 2) + mf * 16 + lo;
        int pos = (kf * 4 + lg) ^ (row & 7);
        af[mf] = *(const bf16x8*)((const char*)Asm + row * 128 + pos * 16);
      }
#pragma unroll
      for (int nf = 0; nf < 4; ++nf) {
        int row = wc * 64 + nf * 16 + lo;
        int pos = (kf * 4 + lg) ^ (row & 7);
        bfr[nf] = *(const bf16x8*)((const char*)Bsm + row * 128 + pos * 16);
      }
#pragma unroll
      for (int mf = 0; mf < MFR; ++mf)
#pragma unroll
        for (int nf = 0; nf < 4; ++nf)
          acc[mf][nf] = mfma16(af[mf], bfr[nf], acc[mf][nf]);
    }
    SBAR();  // all waves done reading before restage
  }

  // epilogue
#pragma unroll
  for (int mf = 0; mf < MFR; ++mf)
#pragma unroll
    for (int nf = 0; nf < 4; ++nf) {
      int gcol = n0 + wc * 64 + nf * 16 + lo;
      float bv = bias[gcol];
#pragma unroll
      for (int r = 0; r < 4; ++r) {
        int grow = m0 + wr * (BM / 2) + mf * 16 + lg * 4 + r;
        float v = (acc[mf][nf][r] + bv) * scale;
        if (mode == 2) {
          ((float*)J.out[g])[((size_t)grow << 10) + gcol] = v;
        } else {
          int b = grow >> 11, s = grow & 2047, h = gcol >> 6, dk = gcol & 63;
          size_t idx;
          if (mode == 0) idx = ((((size_t)((b << 4) + h) << 11) + s) << 6) + dk;
          else           idx = ((((size_t)((b << 4) + h) << 6) + dk) << 11) + s;
          ((__bf16*)J.out[g])[idx] = (__bf16)v;
        }
      }
    }
}

// ---------------- flash attention: 8 waves x 16 q-rows, swapped QK^T ----------------
// Qb: [B*H][S][64] bf16. Kb: same, pre-scaled by 0.125*log2(e). Vt: [B*H][64][S] bf16.
// 1D grid 512 (XCD-swizzled -> bh, qtile), 512 threads. QBLK=128, KVBLK=64, dbuf K/V.
__global__ __launch_bounds__(512, 2) void attn_kernel(const unsigned short* __restrict__ Qb,
                                                      const unsigned short* __restrict__ Kb,
                                                      const unsigned short* __restrict__ Vt,
                                                      unsigned short* __restrict__ ctx) {
  __shared__ alignas(16) unsigned short Ksm[2][64 * 64];  // [kv][64dk] swizzled, dbuf (16KB)
  __shared__ alignas(16) unsigned short Vsm[2][64 * 64];  // [dk][64kv] swizzled, dbuf (16KB)
  __shared__ alignas(16) unsigned short Psm[8 * 16 * 64]; // per-wave [16q][64kv] swizzled (16KB)
  const int tid = threadIdx.x;
  const int l = tid & 63, w = tid >> 6;   // 8 waves
  const int lg = l >> 4, lo = l & 15;
  const int sw = lo & 7;

  // XCD swizzle: 512 blocks, chunk 64 -> each XCD owns 4 complete heads
  const int id = blockIdx.x;
  const int swz = (id & 7) * 64 + (id >> 3);
  const int bh = swz >> 4;
  const int qt = swz & 15;

  const unsigned short* Qp = Qb + (size_t)bh * SEQ * 64;
  const unsigned short* Kp = Kb + (size_t)bh * SEQ * 64;
  const unsigned short* Vp = Vt + (size_t)bh * 64 * SEQ;
  const int q0 = qt * 128 + w * 16;

  // Q fragments: lane holds Q[q0 + lo][kc*32 + lg*8 ..+7]
  bf16x8 qf[2];
#pragma unroll
  for (int kc = 0; kc < 2; ++kc)
    qf[kc] = *(const bf16x8*)((const char*)Qp + (((size_t)(q0 + lo)) << 7) + kc * 64 + lg * 16);
  WAITV0;  // Q loads retired before counted-vmcnt pipeline starts

  f32x4 O[4] = {};
  float m_ = -1e30f, l_ = 0.f;

  // stage K/V tile t into buffer b: 512 threads, 1 K chunk + 1 V chunk each (2 gll/lane)
#define ASTAGE(b, t)                                                                      \
  do {                                                                                    \
    const int kv0s = (t) << 6;                                                            \
    int row = tid >> 3, c = tid & 7;                                                      \
    const char* ksrc = (const char*)Kp + ((size_t)(kv0s + row) << 7) + ((c ^ (row & 7)) << 4); \
    gll16(ksrc, (char*)Ksm[b] + ((tid & ~63) << 4));                                      \
    const char* vsrc = (const char*)Vp + ((size_t)row << 12) + (kv0s << 1) + ((c ^ (row & 7)) << 4); \
    gll16(vsrc, (char*)Vsm[b] + ((tid & ~63) << 4));                                      \
  } while (0)

  ASTAGE(0, 0);

  for (int t = 0; t < SEQ / 64; ++t) {
    const int cur = t & 1;
    if (t < SEQ / 64 - 1) {
      ASTAGE(cur ^ 1, t + 1);
      WAITV2;          // current tile's 2 loads done; next tile's 2 in flight
    } else {
      WAITV0;
    }
    SBAR();

    // S^T = K Q^T : sfr[kvf][r] = S[kv=kvf*16+lg*4+r][q=lo]
    f32x4 sfr[4] = {};
#pragma unroll
    for (int kc = 0; kc < 2; ++kc) {
      bf16x8 kfr[4];
#pragma unroll
      for (int kvf = 0; kvf < 4; ++kvf) {
        int kv = kvf * 16 + lo;
        int pos = (kc * 4 + lg) ^ (kv & 7);
        kfr[kvf] = *(const bf16x8*)((const char*)Ksm[cur] + kv * 128 + pos * 16);
      }
#pragma unroll
      for (int kvf = 0; kvf < 4; ++kvf)
        sfr[kvf] = mfma16(kfr[kvf], qf[kc], sfr[kvf]);
    }

    // online softmax: lane owns q = lo, 16 S-values (kv = kvf*16 + lg*4 + r)
    float a0 = fmaxf(fmaxf(sfr[0][0], sfr[0][1]), fmaxf(sfr[0][2], sfr[0][3]));
    float a1 = fmaxf(fmaxf(sfr[1][0], sfr[1][1]), fmaxf(sfr[1][2], sfr[1][3]));
    float a2 = fmaxf(fmaxf(sfr[2][0], sfr[2][1]), fmaxf(sfr[2][2], sfr[2][3]));
    float a3 = fmaxf(fmaxf(sfr[3][0], sfr[3][1]), fmaxf(sfr[3][2], sfr[3][3]));
    float mx = fmaxf(fmaxf(a0, a1), fmaxf(a2, a3));
    mx = fmaxf(mx, __shfl_xor(mx, 16));
    mx = fmaxf(mx, __shfl_xor(mx, 32));

    if (__any((int)(mx > m_))) {
      float mnew = fmaxf(m_, mx);
      float fac = EXP2(m_ - mnew);
      m_ = mnew;
      float ps = 0.f;
#pragma unroll
      for (int kvf = 0; kvf < 4; ++kvf)
#pragma unroll
        for (int r = 0; r < 4; ++r) {
          float p = EXP2(sfr[kvf][r] - mnew);
          sfr[kvf][r] = p;
          ps += p;
        }
      ps += __shfl_xor(ps, 16);
      ps += __shfl_xor(ps, 32);
      l_ = l_ * fac + ps;
#pragma unroll
      for (int r = 0; r < 4; ++r) {
        float fb = __shfl(fac, lg * 4 + r);
#pragma unroll
        for (int dkf = 0; dkf < 4; ++dkf) O[dkf][r] *= fb;
      }
    } else {
      float ps = 0.f;
#pragma unroll
      for (int kvf = 0; kvf < 4; ++kvf)
#pragma unroll
        for (int r = 0; r < 4; ++r) {
          float p = EXP2(sfr[kvf][r] - m_);
          sfr[kvf][r] = p;
          ps += p;
        }
      ps += __shfl_xor(ps, 16);
      ps += __shfl_xor(ps, 32);
      l_ += ps;
    }

    // pack P -> per-wave swizzled LDS [16q][64kv]
#pragma unroll
    for (int kvf = 0; kvf < 4; ++kvf) {
      union { __bf16 b[4]; unsigned long long u; } pk;
#pragma unroll
      for (int r = 0; r < 4; ++r) pk.b[r] = (__bf16)sfr[kvf][r];
      int g = kvf * 2 + (lg >> 1);
      *(unsigned long long*)((char*)Psm + w * 2048 + lo * 128 + ((g ^ sw) << 4) + ((lg & 1) << 3)) = pk.u;
    }

    // O += P V : A-frags from Psm (q rows), B-frags from Vsm (dk cols)
    bf16x8 af[2];
#pragma unroll
    for (int kc = 0; kc < 2; ++kc) {
      int pos = (kc * 4 + lg) ^ sw;
      af[kc] = *(const bf16x8*)((const char*)Psm + w * 2048 + lo * 128 + pos * 16);
    }
#pragma unroll
    for (int dkf = 0; dkf < 4; ++dkf) {
      int dk = dkf * 16 + lo;
      int pos0 = lg ^ (dk & 7);
      int pos1 = (4 + lg) ^ (dk & 7);
      bf16x8 bv0 = *(const bf16x8*)((const char*)Vsm[cur] + dk * 128 + pos0 * 16);
      bf16x8 bv1 = *(const bf16x8*)((const char*)Vsm[cur] + dk * 128 + pos1 * 16);
      O[dkf] = mfma16(af[0], bv0, O[dkf]);
      O[dkf] = mfma16(af[1], bv1, O[dkf]);
    }
    SBAR();  // all waves done reading buf[cur] before restage
  }
#undef ASTAGE

  // epilogue: normalize and store ctx [B*S][1024]
  const int b = bh >> 4, h = bh & 15;
#pragma unroll
  for (int r = 0; r < 4; ++r) {
    float lr = __shfl(l_, lg * 4 + r);
    float inv = 1.f / lr;
    int srow = q0 + lg * 4 + r;
    size_t rowoff = ((size_t)(b * SEQ + srow) << 10) + h * 64;
#pragma unroll
    for (int dkf = 0; dkf < 4; ++dkf)
      ((__bf16*)ctx)[rowoff + dkf * 16 + lo] = (__bf16)(O[dkf][r] * inv);
  }
}

// ---------------- launch ----------------
extern "C" void kernel_launch(void* const* d_in, const int* in_sizes, int n_in,
                              void* d_out, int out_size, void* d_ws, size_t ws_size,
                              hipStream_t stream) {
  const float* query = (const float*)d_in[0];
  const float* key_  = (const float*)d_in[1];
  const float* value = (const float*)d_in[2];
  const float* wq = (const float*)d_in[4];
  const float* bq = (const float*)d_in[5];
  const float* wk = (const float*)d_in[6];
  const float* bk = (const float*)d_in[7];
  const float* wv = (const float*)d_in[8];
  const float* bv = (const float*)d_in[9];
  const float* wo = (const float*)d_in[10];
  const float* bo = (const float*)d_in[11];

  char* ws = (char*)d_ws;
  unsigned short* xq  = (unsigned short*)(ws + 0);
  unsigned short* xk  = (unsigned short*)(ws + 8388608);
  unsigned short* xv  = (unsigned short*)(ws + 16777216);
  unsigned short* wqb = (unsigned short*)(ws + 25165824);
  unsigned short* wkb = (unsigned short*)(ws + 27262976);
  unsigned short* wvb = (unsigned short*)(ws + 29360128);
  unsigned short* wob = (unsigned short*)(ws + 31457280);
  unsigned short* Qb  = (unsigned short*)(ws + 33554432);   // [B,H,S,64]
  unsigned short* Kb  = (unsigned short*)(ws + 41943040);   // [B,H,S,64] (pre-scaled, log2e folded)
  unsigned short* Vb  = (unsigned short*)(ws + 50331648);   // [B,H,64,S]
  unsigned short* ctx = (unsigned short*)(ws + 58720256);   // [B*S,1024]

  CvtJobs cj;
  cj.s[0] = query; cj.d[0] = xq;  cj.n4[0] = 1048576;
  cj.s[1] = key_;  cj.d[1] = xk;  cj.n4[1] = 1048576;
  cj.s[2] = value; cj.d[2] = xv;  cj.n4[2] = 1048576;
  cj.s[3] = wq;    cj.d[3] = wqb; cj.n4[3] = 262144;
  cj.s[4] = wk;    cj.d[4] = wkb; cj.n4[4] = 262144;
  cj.s[5] = wv;    cj.d[5] = wvb; cj.n4[5] = 262144;
  cj.s[6] = wo;    cj.d[6] = wob; cj.n4[6] = 262144;
  cvt_all<<<dim3(256, 7), 256, 0, stream>>>(cj);

  const float kscale = 0.125f * 1.44269504088896340736f;
  GemmJobs gj;
  gj.A[0] = xq; gj.W[0] = wqb; gj.bias[0] = bq; gj.out[0] = (void*)Qb; gj.scale[0] = 1.0f;   gj.mode[0] = 0;
  gj.A[1] = xk; gj.W[1] = wkb; gj.bias[1] = bk; gj.out[1] = (void*)Kb; gj.scale[1] = kscale; gj.mode[1] = 0;
  gj.A[2] = xv; gj.W[2] = wvb; gj.bias[2] = bv; gj.out[2] = (void*)Vb; gj.scale[2] = 1.0f;   gj.mode[2] = 1;
  gemm_t<128, 256><<<768, 256, 0, stream>>>(gj);   // 3 blocks/CU, balanced

  attn_kernel<<<512, 512, 0, stream>>>(Qb, Kb, Vb, ctx);

  GemmJobs oj;
  oj.A[0] = ctx; oj.W[0] = wob; oj.bias[0] = bo; oj.out[0] = d_out; oj.scale[0] = 1.0f; oj.mode[0] = 2;
  oj.A[1] = oj.A[0]; oj.W[1] = oj.W[0]; oj.bias[1] = oj.bias[0]; oj.out[1] = oj.out[0]; oj.scale[1] = 1.0f; oj.mode[1] = 2;
  oj.A[2] = oj.A[0]; oj.W[2] = oj.W[0]; oj.bias[2] = oj.bias[0]; oj.out[2] = oj.out[0]; oj.scale[2] = 1.0f; oj.mode[2] = 2;
  gemm_t<64, 512><<<512, 256, 0, stream>>>(oj);    // 2 blocks/CU, balanced
}